// Round 4
// baseline (2022.632 us; speedup 1.0000x reference)
//
#include <hip/hip_runtime.h>
#include <cstdint>
#include <cstddef>

// Problem constants
#define B_SZ 512
#define S_SZ 120
#define D_SZ 216
#define H_SZ 1024
#define NG   4096     // 4*H
#define DP   256      // D padded
#define TMAX 24

// GEMM tile config: block 64(M) x 128(N), BK=64, 4 waves 1x4 (wave = 64M x 32N)
#define BM 64
#define BN 128
#define BK 64

using bf16_t = __bf16;
using bf16x8 = __attribute__((ext_vector_type(8))) __bf16;
using f32x4  = __attribute__((ext_vector_type(4))) float;

__device__ __forceinline__ void gload16(const void* g, void* l) {
  __builtin_amdgcn_global_load_lds(
      (const __attribute__((address_space(1))) void*)g,
      (__attribute__((address_space(3))) void*)l, 16, 0, 0);
}

__device__ __forceinline__ float fsigmoid(float x) {
  x = fminf(fmaxf(x, -30.f), 30.f);
  return 1.f / (1.f + __expf(-x));
}
__device__ __forceinline__ float ftanh(float x) {
  x = fminf(fmaxf(x, -15.f), 15.f);
  float e = __expf(2.f * x);
  return (e - 1.f) / (e + 1.f);
}

// LDS: two A-staging buffers (6 segs x 64 rows x 128 B = 48 KB each).
// A stored [seg][row][128B] with XOR 16B-chunk swizzle on the GLOBAL side:
// LDS slot (row, c) holds global chunk c ^ (row&7). gate[] unions over buf1.
struct __align__(16) Smem {
  union {
    bf16_t bufs[2][6 * 64 * 64];                      // 2 x 49152 B
    struct { char pad[49152]; float gate[64 * 129]; } g;
  };
};

// Weight swizzled layout ("fragment-major"): for frag (nb = n>>4, kb = k>>5):
// chunk lane l = ((k>>3)&3)*16 + (n&15), 8 k-contiguous bf16 per lane.
// flat 16B-chunk id = (nb*KB + kb)*64 + l, KB = K/32.

// C[m][n] = sum_k A[m][k] * W[n][k]. A phase1 = A1 (N1 BK-iters), then A2.
// EPI=1: LSTM cell (bias, cbuf fp32 RMW, hout bf16); N gate-interleaved.
// EPI=2: Wdec build: out swizzled bf16 = acc + addm[orig(m)][n]
// EPI=3: outf[(b*24+t)*216+n] = acc + bias[n], m = t*512+b, guard n<216
template <int EPI, int N1, int N2>
__global__ __launch_bounds__(256, 1) void gemm_step(
    const bf16_t* __restrict__ A1, int sA1,
    const bf16_t* __restrict__ A2, int sA2,
    const bf16_t* __restrict__ Wsw,
    const float* __restrict__ bias,
    float* __restrict__ cbuf, bf16_t* __restrict__ hout,
    const float* __restrict__ addm, bf16_t* __restrict__ outb,
    float* __restrict__ outf)
{
  constexpr int NTOT = N1 + N2;
  constexpr int KB   = NTOT * 2;
  constexpr int C0 = NTOT < 4 ? NTOT : 4;
  constexpr int R0 = NTOT - C0;
  constexpr int C1 = R0 < 6 ? R0 : 6;
  constexpr int R1 = R0 - C1;
  constexpr int C2 = R1 < 6 ? R1 : 6;
  constexpr int C3 = R1 - C2;
  static_assert(C3 <= 6, "chunk overflow");

  __shared__ Smem sm;
  const int t    = threadIdx.x;
  const int m0   = blockIdx.y * BM;
  const int n0   = blockIdx.x * BN;
  const int lane = t & 63;
  const int wv   = t >> 6;           // wave id = N-quarter (1x4 wave grid)
  const int fr   = lane & 15;
  const int fq   = lane >> 4;

  f32x4 acc[4][2] = {};              // [mi 0..3][nj 0..1]

  // Epilogue bias prefetch
  float bias2[2] = {0.f, 0.f};
  if (EPI == 1 || EPI == 3) {
#pragma unroll
    for (int nj = 0; nj < 2; ++nj) {
      int col = n0 + wv * 32 + nj * 16 + fr;
      bias2[nj] = (EPI == 3 && col >= D_SZ) ? 0.f : bias[col];
    }
  }

  // ---- A staging: chunk ci (csz segs) from k-offset kst ----
  auto stageChunk = [&](int ci, int kst, int csz) {
    const bf16_t* Ap; int sA; int kloc;
    if (ci == 0 && N1 > 0) { Ap = A1; sA = sA1; kloc = 0; }
    else                   { Ap = A2; sA = sA2; kloc = kst - N1 * BK; }
    char* base = (char*)&sm.bufs[ci & 1][0];
    const int row8 = t >> 3;             // 0..31 (wave wv covers rows wv*8..+7)
    const int c16s = (t & 7);
#pragma unroll
    for (int half = 0; half < 2; ++half) {
      int row = half * 32 + row8;
      int gc  = (c16s ^ (row & 7)) * 8;
      const bf16_t* ga = Ap + (size_t)(m0 + row) * sA + kloc + gc;
      char* ldst = base + (half * 32 + wv * 8) * 128;
      for (int seg = 0; seg < csz; ++seg)
        gload16(ga + seg * 64, ldst + seg * 8192);
    }
  };

  // ---- B fragment register loads (swizzled, coalesced 1KB/wave-instr) ----
  const int nb0 = (n0 >> 4) + wv * 2;
  auto loadB = [&](int it, bf16x8* Bv) {
#pragma unroll
    for (int nj = 0; nj < 2; ++nj)
#pragma unroll
      for (int kk = 0; kk < 2; ++kk)
        Bv[nj * 2 + kk] = *(const bf16x8*)((const char*)Wsw +
            ((size_t)((nb0 + nj) * KB + it * 2 + kk) * 64 + lane) * 16);
  };

  // ---- compute one BK iter from LDS seg + B regs ----
  auto compute = [&](const bf16x8* Bv, int bufi, int seg) {
    const char* base = (const char*)&sm.bufs[bufi][0] + seg * 8192;
#pragma unroll
    for (int kk = 0; kk < 2; ++kk)
#pragma unroll
      for (int mi = 0; mi < 4; ++mi) {
        int row = mi * 16 + fr;
        bf16x8 av = *(const bf16x8*)(base + row * 128 +
                                     (((kk * 4 + fq) ^ (row & 7)) * 16));
        acc[mi][0] = __builtin_amdgcn_mfma_f32_16x16x32_bf16(av, Bv[kk],     acc[mi][0], 0, 0, 0);
        acc[mi][1] = __builtin_amdgcn_mfma_f32_16x16x32_bf16(av, Bv[2 + kk], acc[mi][1], 0, 0, 0);
      }
  };

  bf16x8 Bv[2][4];
  loadB(0, Bv[0]);
  stageChunk(0, 0, C0);
  __syncthreads();
  if (C1 > 0) stageChunk(1, C0 * BK, C1);
#pragma unroll
  for (int i = 0; i < C0; ++i) {
    if (i + 1 < NTOT) loadB(i + 1, Bv[(i + 1) & 1]);
    compute(Bv[i & 1], 0, i);
  }
  if (C1 > 0) {
    __syncthreads();
    if (C2 > 0) stageChunk(2, (C0 + C1) * BK, C2);
#pragma unroll
    for (int i = 0; i < C1; ++i) {
      int it = C0 + i;
      if (it + 1 < NTOT) loadB(it + 1, Bv[(it + 1) & 1]);
      compute(Bv[it & 1], 1, i);
    }
  }
  if (C2 > 0) {
    __syncthreads();
    if (C3 > 0) stageChunk(3, (C0 + C1 + C2) * BK, C3);
#pragma unroll
    for (int i = 0; i < C2; ++i) {
      int it = C0 + C1 + i;
      if (it + 1 < NTOT) loadB(it + 1, Bv[(it + 1) & 1]);
      compute(Bv[it & 1], 0, i);
    }
  }
  if (C3 > 0) {
    __syncthreads();
#pragma unroll
    for (int i = 0; i < C3; ++i) {
      int it = C0 + C1 + C2 + i;
      if (it + 1 < NTOT) loadB(it + 1, Bv[(it + 1) & 1]);
      compute(Bv[it & 1], 1, i);
    }
  }
  __syncthreads();   // A reads done; gate[] (over buf1) now safe

  if (EPI == 1) {
    // acc -> LDS gate tile (fp32, +bias), then LSTM cell.
#pragma unroll
    for (int mi = 0; mi < 4; ++mi)
#pragma unroll
      for (int nj = 0; nj < 2; ++nj)
#pragma unroll
        for (int v = 0; v < 4; ++v) {
          int row = mi * 16 + fq * 4 + v;
          int col = wv * 32 + nj * 16 + fr;
          sm.g.gate[row * 129 + col] = acc[mi][nj][v] + bias2[nj];
        }
    __syncthreads();
    const int u0 = n0 >> 2;
#pragma unroll
    for (int itc = 0; itc < 8; ++itc) {
      int ci = itc * 256 + t;
      int brw = ci >> 5;   // 0..63 local batch row
      int ju  = ci & 31;   // 0..31 local unit
      const float* gp = &sm.g.gate[brw * 129 + ju * 4];
      float iv = fsigmoid(gp[0]);
      float fv = fsigmoid(gp[1]);
      float gv = ftanh(gp[2]);
      float ov = fsigmoid(gp[3]);
      size_t cix = (size_t)(m0 + brw) * H_SZ + (u0 + ju);
      float cn = fv * cbuf[cix] + iv * gv;
      cbuf[cix] = cn;
      hout[cix] = (bf16_t)(ov * ftanh(cn));
    }
  }

  if (EPI == 2) {
    // acc + addm -> gate LDS, then swizzled coalesced 16B-chunk writes.
#pragma unroll
    for (int mi = 0; mi < 4; ++mi)
#pragma unroll
      for (int nj = 0; nj < 2; ++nj)
#pragma unroll
        for (int v = 0; v < 4; ++v) {
          int row = mi * 16 + fq * 4 + v;
          int col = wv * 32 + nj * 16 + fr;
          int gr = m0 + row, gc = n0 + col;
          int orig = (gr & 3) * H_SZ + (gr >> 2);
          sm.g.gate[row * 129 + col] = acc[mi][nj][v] + addm[(size_t)orig * H_SZ + gc];
        }
    __syncthreads();
#pragma unroll
    for (int q = 0; q < 4; ++q) {
      int c = q * 256 + t;             // 0..1023 local chunks
      int nbl = c >> 8, kbl = (c >> 6) & 3, l2 = c & 63;
      int nloc = nbl * 16 + (l2 & 15);
      int kloc = kbl * 32 + (l2 >> 4) * 8;
      const float* gp = &sm.g.gate[nloc * 129 + kloc];
      bf16x8 v;
#pragma unroll
      for (int j = 0; j < 8; ++j) v[j] = (bf16_t)gp[j];
      size_t chunk = (size_t)(((m0 >> 4) + nbl) * 32 + (n0 >> 5) + kbl) * 64 + l2;
      *(bf16x8*)(outb + chunk * 8) = v;
    }
  }

  if (EPI == 3) {
#pragma unroll
    for (int mi = 0; mi < 4; ++mi)
#pragma unroll
      for (int nj = 0; nj < 2; ++nj)
#pragma unroll
        for (int v = 0; v < 4; ++v) {
          int m = m0 + mi * 16 + fq * 4 + v;
          int n = n0 + wv * 32 + nj * 16 + fr;
          if (n < D_SZ) {
            outf[((size_t)(m & 511) * TMAX + (m >> 9)) * D_SZ + n] =
                acc[mi][nj][v] + bias2[nj];
          }
        }
  }
}

// src (B,S,D) fp32 -> srcbf (S,B,DP) bf16, zero-padded
__global__ void k_convert_src(const float* __restrict__ src, bf16_t* __restrict__ dst) {
  int idx = blockIdx.x * 256 + threadIdx.x;
  int total = S_SZ * B_SZ * DP;
  if (idx >= total) return;
  int d = idx % DP;
  int r = idx / DP;
  int b = r % B_SZ;
  int tt = r / B_SZ;
  float v = (d < D_SZ) ? src[((size_t)b * S_SZ + tt) * D_SZ + d] : 0.f;
  dst[idx] = (bf16_t)v;
}

// Swizzled W_cat (N=4096 gate-interleaved rows, K=1280: [Wih|0|Whh]), KB=40
__global__ void k_build_wcat_sw(const float* __restrict__ Wih, const float* __restrict__ Whh,
                                bf16_t* __restrict__ out) {
  int c = blockIdx.x * 256 + threadIdx.x;
  if (c >= 256 * 40 * 64) return;
  int l = c & 63;
  int kb = (c >> 6) % 40;
  int nb = c / (40 * 64);
  int n = nb * 16 + (l & 15);
  int k0 = kb * 32 + (l >> 4) * 8;
  int o = (n & 3) * H_SZ + (n >> 2);
  bf16x8 v;
#pragma unroll
  for (int j = 0; j < 8; ++j) {
    int k = k0 + j;
    float x = (k < D_SZ) ? Wih[(size_t)o * D_SZ + k]
            : (k < DP ? 0.f : Whh[(size_t)o * H_SZ + (k - DP)]);
    v[j] = (bf16_t)x;
  }
  *(bf16x8*)(out + (size_t)c * 8) = v;
}

// Swizzled B for Wdec build: B[n=h 0..1023][k=d 0..255] = Wout[d][h], KB=8
__global__ void k_build_woutt_sw(const float* __restrict__ Wout, bf16_t* __restrict__ out) {
  int c = blockIdx.x * 256 + threadIdx.x;
  if (c >= 64 * 8 * 64) return;
  int l = c & 63;
  int kb = (c >> 6) % 8;
  int nb = c / (8 * 64);
  int n = nb * 16 + (l & 15);          // h
  int k0 = kb * 32 + (l >> 4) * 8;     // d
  bf16x8 v;
#pragma unroll
  for (int j = 0; j < 8; ++j) {
    int k = k0 + j;
    v[j] = (bf16_t)((k < D_SZ) ? Wout[(size_t)k * H_SZ + n] : 0.f);
  }
  *(bf16x8*)(out + (size_t)c * 8) = v;
}

// Swizzled B for final projection: B[n=d 0..255][k=h 0..1023] = Wout[d][h], KB=32
__global__ void k_build_wout_sw(const float* __restrict__ Wout, bf16_t* __restrict__ out) {
  int c = blockIdx.x * 256 + threadIdx.x;
  if (c >= 16 * 32 * 64) return;
  int l = c & 63;
  int kb = (c >> 6) % 32;
  int nb = c / (32 * 64);
  int n = nb * 16 + (l & 15);          // d
  int k0 = kb * 32 + (l >> 4) * 8;     // h
  bf16x8 v;
#pragma unroll
  for (int j = 0; j < 8; ++j)
    v[j] = (bf16_t)((n < D_SZ) ? Wout[(size_t)n * H_SZ + k0 + j] : 0.f);
  *(bf16x8*)(out + (size_t)c * 8) = v;
}

// Natural A for Wdec build: [4096 gate rows][256 d-pad] bf16
__global__ void k_build_wihre(const float* __restrict__ Wih, bf16_t* __restrict__ out) {
  int c = blockIdx.x * 256 + threadIdx.x;
  if (c >= 4096 * 32) return;
  int r = c >> 5;
  int k0 = (c & 31) * 8;
  int o = (r & 3) * H_SZ + (r >> 2);
  bf16x8 v;
#pragma unroll
  for (int j = 0; j < 8; ++j) {
    int k = k0 + j;
    v[j] = (bf16_t)((k < D_SZ) ? Wih[(size_t)o * D_SZ + k] : 0.f);
  }
  *(bf16x8*)(out + (size_t)c * 8) = v;
}

// bias_enc[r] = b_ih[o]+b_hh[o];  bias_dec[r] = bias_enc[r] + W_ih[o,:].b_out
__global__ void k_build_bias(const float* __restrict__ bih, const float* __restrict__ bhh,
                             const float* __restrict__ Wih, const float* __restrict__ bout,
                             float* __restrict__ biasE, float* __restrict__ biasD) {
  int r = blockIdx.x * 256 + threadIdx.x;
  if (r >= NG) return;
  int o = (r & 3) * H_SZ + (r >> 2);
  float be = bih[o] + bhh[o];
  biasE[r] = be;
  float s = 0.f;
  const float* wr = Wih + (size_t)o * D_SZ;
  for (int d = 0; d < D_SZ; ++d) s += wr[d] * bout[d];
  biasD[r] = be + s;
}

extern "C" void kernel_launch(void* const* d_in, const int* in_sizes, int n_in,
                              void* d_out, int out_size, void* d_ws, size_t ws_size,
                              hipStream_t stream) {
  const float* src  = (const float*)d_in[0];
  const float* Wih  = (const float*)d_in[1];
  const float* Whh  = (const float*)d_in[2];
  const float* bih  = (const float*)d_in[3];
  const float* bhh  = (const float*)d_in[4];
  const float* Wout = (const float*)d_in[5];
  const float* bout = (const float*)d_in[6];

  char* ws = (char*)d_ws;
  size_t off = 0;
  auto alloc = [&](size_t bytes) {
    void* p = ws + off;
    off = (off + bytes + 255) & ~(size_t)255;
    return p;
  };
  bf16_t* srcbf  = (bf16_t*)alloc((size_t)S_SZ * B_SZ * DP * 2);   // 31.5 MB
  bf16_t* WcatSw = (bf16_t*)alloc((size_t)256 * 40 * 64 * 16);     // 10.5 MB
  bf16_t* WdecSw = (bf16_t*)alloc((size_t)NG * H_SZ * 2);          //  8.4 MB
  bf16_t* WouttSw= (bf16_t*)alloc((size_t)64 * 8 * 64 * 16);
  bf16_t* WoutSw = (bf16_t*)alloc((size_t)16 * 32 * 64 * 16);
  bf16_t* WihRe  = (bf16_t*)alloc((size_t)NG * DP * 2);            //  2 MB
  float*  biasE  = (float*)alloc((size_t)NG * 4);
  float*  biasD  = (float*)alloc((size_t)NG * 4);
  float*  cbuf   = (float*)alloc((size_t)B_SZ * H_SZ * 4);         //  2 MB
  bf16_t* hP0    = (bf16_t*)alloc((size_t)B_SZ * H_SZ * 2);
  bf16_t* hP1    = (bf16_t*)alloc((size_t)B_SZ * H_SZ * 2);
  bf16_t* Hs     = (bf16_t*)alloc((size_t)TMAX * B_SZ * H_SZ * 2); // 25.2 MB

  hipMemsetAsync(cbuf, 0, (size_t)B_SZ * H_SZ * 4, stream);
  hipMemsetAsync(hP0, 0, (size_t)B_SZ * H_SZ * 2, stream);

  k_convert_src<<<(S_SZ * B_SZ * DP + 255) / 256, 256, 0, stream>>>(src, srcbf);
  k_build_wcat_sw<<<(256 * 40 * 64 + 255) / 256, 256, 0, stream>>>(Wih, Whh, WcatSw);
  k_build_woutt_sw<<<(64 * 8 * 64 + 255) / 256, 256, 0, stream>>>(Wout, WouttSw);
  k_build_wout_sw<<<(16 * 32 * 64 + 255) / 256, 256, 0, stream>>>(Wout, WoutSw);
  k_build_wihre<<<(4096 * 32 + 255) / 256, 256, 0, stream>>>(Wih, WihRe);
  k_build_bias<<<(NG + 255) / 256, 256, 0, stream>>>(bih, bhh, Wih, bout, biasE, biasD);

  // W_dec(swizzled) = Whh_reord + Wih_reord @ Wout  (M=4096, N=1024, K=256)
  gemm_step<2, 4, 0><<<dim3(H_SZ / BN, NG / BM), 256, 0, stream>>>(
      WihRe, DP, nullptr, 0, WouttSw, nullptr,
      nullptr, nullptr, Whh, WdecSw, nullptr);

  // 120 encoder steps + decoder step 0 (x = src_t[119]) + 23 folded dec steps
  const bf16_t* hprev = hP0;
  for (int s = 0; s < 144; ++s) {
    bf16_t* hnext;
    if (s < 120) hnext = (hprev == hP0) ? hP1 : hP0;
    else         hnext = Hs + (size_t)(s - 120) * B_SZ * H_SZ;
    if (s <= 120) {
      int xi = (s <= 119) ? s : 119;
      gemm_step<1, 4, 16><<<dim3(NG / BN, B_SZ / BM), 256, 0, stream>>>(
          srcbf + (size_t)xi * B_SZ * DP, DP, hprev, H_SZ,
          WcatSw, biasE, cbuf, hnext, nullptr, nullptr, nullptr);
    } else {
      gemm_step<1, 0, 16><<<dim3(NG / BN, B_SZ / BM), 256, 0, stream>>>(
          nullptr, 0, hprev, H_SZ,
          WdecSw, biasD, cbuf, hnext, nullptr, nullptr, nullptr);
    }
    hprev = hnext;
  }

  // Final projection: Y(12288 x 216) = Hs(12288 x 1024) @ Wout^T + b_out
  gemm_step<3, 0, 16><<<dim3(2, (TMAX * B_SZ) / BM), 256, 0, stream>>>(
      nullptr, 0, Hs, H_SZ, WoutSw, bout,
      nullptr, nullptr, nullptr, nullptr, (float*)d_out);
}